// Round 2
// baseline (10237.315 us; speedup 1.0000x reference)
//
#include <hip/hip_runtime.h>
#include <math.h>

#define B 32
#define E 512
#define CTXD 512
#define H 1024
#define G4 4096      // 4*H
#define V 32000
#define T 64
#define LDW 1024     // row length (in floats) of every weight matrix here
#define START_TOK 1

// ---------------- workspace layout (float offsets) ----------------
#define OFF_GCTX   0L          // [B][G4]  ctx@Wih0[:,512:] + b_ih0 + b_hh0
#define OFF_H0     131072L     // [B][H]
#define OFF_C0     163840L
#define OFF_H1     196608L
#define OFF_C1     229376L
#define OFF_PART0  262144L     // [6][B][G4] layer0 K-split partials
#define OFF_PART1  1048576L    // [8][B][G4] layer1 K-split partials
#define OFF_BSUM1  2097152L    // [G4]  b_ih1 + b_hh1
#define OFF_SUMS   2101248L    // [T][B] float softmax denominators
#define OFF_AMAX   2103296L    // [T][B] u64 packed (exp_bits<<32)|(~v)
// total = 2107392 floats = 8.43 MB of d_ws

// ------------------------------------------------------------------
// Skinny GEMM tile: block 256 threads computes C[b][j] for j in [j0,j0+128),
// all 32 b.  Thread: jj=tid&63 (j = j0+jj, j0+jj+64), bg=tid>>6, b = bg+4g.
// W (row-major, row length LDW) staged transposed in LDS (pad +1 -> 2-way max,
// free).  X rows given by per-b pointers (srow).  X reads are wave-broadcast.
// ------------------------------------------------------------------
__device__ __forceinline__ void gemm_tile(
    const float* __restrict__ W, int wcol, int j0, int xcol, int klen, int tid,
    const float* const* srow,
    float (&Wt)[64][129], float (&Xs)[32][64], float (&acc)[2][8])
{
  const int jj = tid & 63;
  const int bg = tid >> 6;
  for (int kc = 0; kc < klen; kc += 64) {
    // stage W tile: 128 rows x 64 cols, transposed
#pragma unroll
    for (int i = 0; i < 8; i++) {
      int fi  = tid + (i << 8);          // 0..2047
      int row = fi >> 4;                  // 0..127
      int c4  = (fi & 15) << 2;           // 0,4,..,60
      const float4 w4 = *(const float4*)(W + (long)(j0 + row) * LDW + (wcol + kc + c4));
      Wt[c4 + 0][row] = w4.x;
      Wt[c4 + 1][row] = w4.y;
      Wt[c4 + 2][row] = w4.z;
      Wt[c4 + 3][row] = w4.w;
    }
    // stage X tile: 32 rows x 64 cols
#pragma unroll
    for (int i = 0; i < 2; i++) {
      int fi = tid + (i << 8);            // 0..511
      int b  = fi >> 4;
      int c4 = (fi & 15) << 2;
      *(float4*)&Xs[b][c4] = *(const float4*)(srow[b] + xcol + kc + c4);
    }
    __syncthreads();
#pragma unroll 4
    for (int k = 0; k < 64; k += 4) {
      float wa0 = Wt[k + 0][jj],      wa1 = Wt[k + 1][jj];
      float wa2 = Wt[k + 2][jj],      wa3 = Wt[k + 3][jj];
      float wb0 = Wt[k + 0][jj + 64], wb1 = Wt[k + 1][jj + 64];
      float wb2 = Wt[k + 2][jj + 64], wb3 = Wt[k + 3][jj + 64];
#pragma unroll
      for (int g = 0; g < 8; g++) {
        const float4 xv = *(const float4*)&Xs[bg + (g << 2)][k];
        float a0 = acc[0][g], a1 = acc[1][g];
        a0 = fmaf(wa0, xv.x, a0); a0 = fmaf(wa1, xv.y, a0);
        a0 = fmaf(wa2, xv.z, a0); a0 = fmaf(wa3, xv.w, a0);
        a1 = fmaf(wb0, xv.x, a1); a1 = fmaf(wb1, xv.y, a1);
        a1 = fmaf(wb2, xv.z, a1); a1 = fmaf(wb3, xv.w, a1);
        acc[0][g] = a0; acc[1][g] = a1;
      }
    }
    __syncthreads();
  }
}

// ---------------- init: zero states/sums/amax, bsum1 ----------------
__global__ void init_kernel(float* __restrict__ ws,
                            const float* __restrict__ bih1,
                            const float* __restrict__ bhh1)
{
  int i = blockIdx.x * 256 + threadIdx.x;      // grid 256x256 = 65536 threads
  // h0,c0,h1,c1 contiguous: floats [OFF_H0, OFF_H0+131072)
  for (int k = i; k < 131072; k += 65536) ws[OFF_H0 + k] = 0.f;
  if (i < 4096) ws[OFF_BSUM1 + i] = bih1[i] + bhh1[i];
  if (i < 2048) ws[OFF_SUMS + i] = 0.f;
  if (i < 4096) ws[OFF_AMAX + i] = 0.f;        // u64 zeros
}

// ---------------- precompute gctx = ctx @ Wih0[:,512:].T + biases ----------------
__global__ void gctx_kernel(float* __restrict__ ws,
                            const float* __restrict__ ctx,
                            const float* __restrict__ Wih0,
                            const float* __restrict__ bih0,
                            const float* __restrict__ bhh0)
{
  __shared__ float Wt[64][129];
  __shared__ float Xs[32][64];
  __shared__ const float* srow[32];
  const int tid = threadIdx.x;
  const int j0  = blockIdx.x * 128;
  if (tid < 32) srow[tid] = ctx + tid * CTXD;
  __syncthreads();
  float acc[2][8] = {};
  gemm_tile(Wih0, /*wcol=*/E, j0, /*xcol=*/0, /*klen=*/CTXD, tid, srow, Wt, Xs, acc);
  const int jj = tid & 63;
  const int bg = tid >> 6;
  const float bsA = bih0[j0 + jj]      + bhh0[j0 + jj];
  const float bsB = bih0[j0 + jj + 64] + bhh0[j0 + jj + 64];
#pragma unroll
  for (int g = 0; g < 8; g++) {
    int b = bg + (g << 2);
    float* o = ws + OFF_GCTX + (long)b * G4 + j0;
    o[jj]      = acc[0][g] + bsA;
    o[jj + 64] = acc[1][g] + bsB;
  }
}

// ---------------- LSTM gate GEMM partials (both layers) ----------------
__global__ void lstm_gemm(int layer, int t,
                          const float* __restrict__ Wih,
                          const float* __restrict__ Whh,
                          const float* __restrict__ emb,
                          float* __restrict__ ws)
{
  __shared__ float Wt[64][129];
  __shared__ float Xs[32][64];
  __shared__ const float* srow[32];
  const int tid = threadIdx.x;
  const int c   = blockIdx.y;
  const int j0  = blockIdx.x * 128;

  const float* W;
  int wcol, xcol;
  if (layer == 0) {
    if (c < 2) { W = Wih; wcol = c * 256; xcol = wcol; }
    else       { W = Whh; wcol = (c - 2) * 256; xcol = wcol; }
  } else {
    if (c < 4) { W = Wih; wcol = c * 256; xcol = wcol; }
    else       { W = Whh; wcol = (c - 4) * 256; xcol = wcol; }
  }
  if (tid < 32) {
    const float* r;
    if (layer == 0 && c < 2) {
      int tok;
      if (t == 0) tok = START_TOK;
      else {
        unsigned long long p = ((const unsigned long long*)(ws + OFF_AMAX))[(long)(t - 1) * B + tid];
        tok = (int)(0xFFFFFFFFu - (unsigned)(p & 0xFFFFFFFFull));
      }
      r = emb + (long)tok * E;
    } else if (layer == 0) {
      r = ws + OFF_H0 + (long)tid * H;
    } else {
      r = ws + (c < 4 ? OFF_H0 : OFF_H1) + (long)tid * H;
    }
    srow[tid] = r;
  }
  __syncthreads();

  float acc[2][8] = {};
  gemm_tile(W, wcol, j0, xcol, /*klen=*/256, tid, srow, Wt, Xs, acc);

  const int jj = tid & 63;
  const int bg = tid >> 6;
  float* part = ws + (layer == 0 ? OFF_PART0 : OFF_PART1) + (long)c * B * G4;
#pragma unroll
  for (int g = 0; g < 8; g++) {
    int b = bg + (g << 2);
    float* o = part + (long)b * G4 + j0;
    o[jj]      = acc[0][g];
    o[jj + 64] = acc[1][g];
  }
}

// ---------------- cell updates ----------------
__global__ void cell0_kernel(float* __restrict__ ws)
{
  int idx = blockIdx.x * 256 + threadIdx.x;   // 0..32767
  int b = idx >> 10, h = idx & 1023;
  const float* gc = ws + OFF_GCTX + (long)b * G4;
  float gi = gc[h], gf = gc[h + 1024], gg = gc[h + 2048], go = gc[h + 3072];
#pragma unroll
  for (int c = 0; c < 6; c++) {
    const float* p = ws + OFF_PART0 + ((long)c * B + b) * G4;
    gi += p[h]; gf += p[h + 1024]; gg += p[h + 2048]; go += p[h + 3072];
  }
  float i_ = 1.f / (1.f + expf(-gi));
  float f_ = 1.f / (1.f + expf(-gf));
  float o_ = 1.f / (1.f + expf(-go));
  float g_ = tanhf(gg);
  float cn = f_ * ws[OFF_C0 + idx] + i_ * g_;
  ws[OFF_C0 + idx] = cn;
  ws[OFF_H0 + idx] = o_ * tanhf(cn);
}

__global__ void cell1_kernel(float* __restrict__ ws)
{
  int idx = blockIdx.x * 256 + threadIdx.x;
  int b = idx >> 10, h = idx & 1023;
  const float* bs = ws + OFF_BSUM1;
  float gi = bs[h], gf = bs[h + 1024], gg = bs[h + 2048], go = bs[h + 3072];
#pragma unroll
  for (int c = 0; c < 8; c++) {
    const float* p = ws + OFF_PART1 + ((long)c * B + b) * G4;
    gi += p[h]; gf += p[h + 1024]; gg += p[h + 2048]; go += p[h + 3072];
  }
  float i_ = 1.f / (1.f + expf(-gi));
  float f_ = 1.f / (1.f + expf(-gf));
  float o_ = 1.f / (1.f + expf(-go));
  float g_ = tanhf(gg);
  float cn = f_ * ws[OFF_C1 + idx] + i_ * g_;
  ws[OFF_C1 + idx] = cn;
  ws[OFF_H1 + idx] = o_ * tanhf(cn);
}

// ---------------- vocab projection + exp + sum/argmax atomics ----------------
__global__ void logits_kernel(float* __restrict__ ws,
                              const float* __restrict__ Wlin,
                              const float* __restrict__ blin,
                              float* __restrict__ out, int t)
{
  __shared__ float Wt[64][129];
  __shared__ float Xs[32][64];
  __shared__ const float* srow[32];
  __shared__ float ssum[32];
  __shared__ unsigned long long smax[32];
  const int tid = threadIdx.x;
  const int j0  = blockIdx.x * 128;
  if (tid < 32) {
    srow[tid] = ws + OFF_H1 + (long)tid * H;
    ssum[tid] = 0.f;
    smax[tid] = 0ull;
  }
  __syncthreads();

  float acc[2][8] = {};
  gemm_tile(Wlin, /*wcol=*/0, j0, /*xcol=*/0, /*klen=*/H, tid, srow, Wt, Xs, acc);

  const int jj = tid & 63;
  const int bg = tid >> 6;
  const float bl0 = blin[j0 + jj];
  const float bl1 = blin[j0 + jj + 64];
#pragma unroll
  for (int g = 0; g < 8; g++) {
    int b = bg + (g << 2);
    float e0 = expf(acc[0][g] + bl0);
    float e1 = expf(acc[1][g] + bl1);
    long obase = ((long)b * T + t) * (long)V + j0;
    out[obase + jj]      = e0;
    out[obase + jj + 64] = e1;
    atomicAdd(&ssum[b], e0 + e1);
    unsigned long long p0 = ((unsigned long long)__float_as_uint(e0) << 32) |
                            (unsigned long long)(0xFFFFFFFFu - (unsigned)(j0 + jj));
    unsigned long long p1 = ((unsigned long long)__float_as_uint(e1) << 32) |
                            (unsigned long long)(0xFFFFFFFFu - (unsigned)(j0 + jj + 64));
    atomicMax(&smax[b], p0 > p1 ? p0 : p1);
  }
  __syncthreads();
  if (tid < 32) {
    atomicAdd(ws + OFF_SUMS + (long)t * B + tid, ssum[tid]);
    atomicMax((unsigned long long*)(ws + OFF_AMAX) + (long)t * B + tid, smax[tid]);
  }
}

// ---------------- normalize probs in-place ----------------
__global__ void norm_kernel(float* __restrict__ out, const float* __restrict__ ws, int t)
{
  int fi = blockIdx.x * 256 + threadIdx.x;   // 0..255999 float4s (32 rows x 8000)
  int b  = fi / 8000;                        // 8000 float4 per row
  int v4 = (fi - b * 8000) << 2;
  float rs = 1.f / ws[OFF_SUMS + (long)t * B + b];
  float4* p = (float4*)(out + ((long)b * T + t) * (long)V + v4);
  float4 x = *p;
  x.x *= rs; x.y *= rs; x.z *= rs; x.w *= rs;
  *p = x;
}

// ---------------- host ----------------
extern "C" void kernel_launch(void* const* d_in, const int* in_sizes, int n_in,
                              void* d_out, int out_size, void* d_ws, size_t ws_size,
                              hipStream_t stream)
{
  const float* context = (const float*)d_in[0];
  // d_in[1] = max_len scalar (fixed 64, hard-coded)
  const float* emb  = (const float*)d_in[2];
  const float* Wih0 = (const float*)d_in[3];
  const float* Whh0 = (const float*)d_in[4];
  const float* bih0 = (const float*)d_in[5];
  const float* bhh0 = (const float*)d_in[6];
  const float* Wih1 = (const float*)d_in[7];
  const float* Whh1 = (const float*)d_in[8];
  const float* bih1 = (const float*)d_in[9];
  const float* bhh1 = (const float*)d_in[10];
  const float* Wlin = (const float*)d_in[11];
  const float* blin = (const float*)d_in[12];
  float* out = (float*)d_out;
  float* ws  = (float*)d_ws;

  init_kernel<<<256, 256, 0, stream>>>(ws, bih1, bhh1);
  gctx_kernel<<<32, 256, 0, stream>>>(ws, context, Wih0, bih0, bhh0);

  for (int t = 0; t < T; t++) {
    lstm_gemm<<<dim3(32, 6), 256, 0, stream>>>(0, t, Wih0, Whh0, emb, ws);
    cell0_kernel<<<128, 256, 0, stream>>>(ws);
    lstm_gemm<<<dim3(32, 8), 256, 0, stream>>>(1, t, Wih1, Whh1, emb, ws);
    cell1_kernel<<<128, 256, 0, stream>>>(ws);
    logits_kernel<<<250, 256, 0, stream>>>(ws, Wlin, blin, out, t);
    norm_kernel<<<1000, 256, 0, stream>>>(out, ws, t);
  }
}